// Round 5
// baseline (15.562 us; speedup 1.0000x reference)
//
#include <hip/hip_runtime.h>

#define B_DIM 2048
#define F_DIM 512
#define U_DIM 256

constexpr float K_L2E = 21.64042561333445f;   // 15 * log2(e)
constexpr float INV_K = 1.0f / K_L2E;

using short8 = __attribute__((ext_vector_type(8))) short;  // 8 bf16 = 4 VGPRs
using f32x4  = __attribute__((ext_vector_type(4))) float;

__device__ __forceinline__ unsigned short f2bf(float f) {
    unsigned u = __float_as_uint(f);
    return (unsigned short)((u + 0x7FFFu + ((u >> 16) & 1u)) >> 16);  // RNE, finite inputs
}

// Single fused kernel: block = (rt, utq) -> 16 rows x 64 units, 4 waves.
// A (exp'd x) staged in LDS (swizzled); B (exp'd w) built per-lane in registers.
__global__ __launch_bounds__(256)
void fused1_k(const float* __restrict__ x, const float* __restrict__ w,
              float* __restrict__ out) {
    __shared__ short8 sA[1024];     // 16 chunks x 64 slots x 16B = 16 KB
    __shared__ float  sst[16];

    const int tid  = threadIdx.x;
    const int wv   = tid >> 6;
    const int lane = tid & 63;
    const int rt   = blockIdx.x >> 2;       // 128 row tiles
    const int utq  = blockIdx.x & 3;
    const int mode = utq >> 1;              // 0: softmax half, 1: softmin half
    const int ut   = (utq << 2) + wv;       // u tile 0..15

    // ---- stage A: load x rows, row-reduce, exp2, write swizzled LDS frags ----
    const int   kb_w = lane >> 2;
    const int   g_w  = lane & 3;
    const float sgn  = mode ? -1.f : 1.f;   // t = sgn*x; max(t) covers both modes

#pragma unroll
    for (int j = 0; j < 4; ++j) {
        const int row = (wv << 2) + j;      // 4 rows per wave -> 16 rows per block
        const float4* xr = reinterpret_cast<const float4*>(x + (rt * 16 + row) * F_DIM);
        float4 v0 = xr[lane * 2];
        float4 v1 = xr[lane * 2 + 1];
        float t[8] = {sgn * v0.x, sgn * v0.y, sgn * v0.z, sgn * v0.w,
                      sgn * v1.x, sgn * v1.y, sgn * v1.z, sgn * v1.w};
        float hi = t[0];
#pragma unroll
        for (int i = 1; i < 8; ++i) hi = fmaxf(hi, t[i]);
#pragma unroll
        for (int off = 32; off; off >>= 1) hi = fmaxf(hi, __shfl_xor(hi, off));
        if (lane == 0) sst[row] = hi;
        short8 cb;
#pragma unroll
        for (int i = 0; i < 8; ++i) cb[i] = (short)f2bf(exp2f(K_L2E * (t[i] - hi)));
        sA[(kb_w << 6) + ((row + (g_w << 4)) ^ (kb_w & 7))] = cb;
    }

    // ---- build B fragments in registers from w (L2-hot, no LDS, no sync) ----
    // lane = (u%16) + 16*g holds k = 8g+i -> f = 32*kb + 8*g + i, u = u0 + lane%16
    const int   uc = (ut << 4) + (lane & 15);
    const int   g  = lane >> 4;
    const float sw = mode ? -K_L2E : K_L2E;
    short8 bfr[16];
#pragma unroll
    for (int kb = 0; kb < 16; ++kb) {
        const float* wp = w + (32 * kb + 8 * g) * U_DIM + uc;
#pragma unroll
        for (int i = 0; i < 8; ++i)
            bfr[kb][i] = (short)f2bf(exp2f(sw * wp[i * U_DIM]));
    }

    __syncthreads();

    // ---- MFMA loop: A from LDS (conflict-free swizzled), B from VGPRs ----
    f32x4 acc = {0.f, 0.f, 0.f, 0.f};
#pragma unroll
    for (int kb = 0; kb < 16; ++kb) {
        short8 a = sA[(kb << 6) + (lane ^ (kb & 7))];
        acc = __builtin_amdgcn_mfma_f32_16x16x32_bf16(a, bfr[kb], acc, 0, 0, 0);
    }

    // ---- epilogue: C/D layout col = lane&15, row = (lane>>4)*4 + r ----
    const int j    = lane & 15;
    const int quad = lane >> 4;
#pragma unroll
    for (int r = 0; r < 4; ++r) {
        const int row = (quad << 2) + r;
        float res = sst[row] + __log2f(acc[r]) * INV_K;
        out[(rt * 16 + row) * U_DIM + (ut << 4) + j] = mode ? -res : res;
    }
}

extern "C" void kernel_launch(void* const* d_in, const int* in_sizes, int n_in,
                              void* d_out, int out_size, void* d_ws, size_t ws_size,
                              hipStream_t stream) {
    const float* x = (const float*)d_in[0];
    const float* w = (const float*)d_in[1];
    float* out = (float*)d_out;
    fused1_k<<<512, 256, 0, stream>>>(x, w, out);
}

// Round 6
// 14.822 us; speedup vs baseline: 1.0499x; 1.0499x over previous
//
#include <hip/hip_runtime.h>
#include <hip/hip_bf16.h>

#define B_DIM 2048
#define F_DIM 512
#define U_DIM 256

constexpr float K_L2E = 21.64042561333445f;   // 15 * log2(e)
constexpr float INV_K = 1.0f / K_L2E;

using short8 = __attribute__((ext_vector_type(8))) short;  // 8 bf16 = 4 VGPRs
using f32x4  = __attribute__((ext_vector_type(4))) float;

__device__ __forceinline__ short f2bf(float f) {
    union { __hip_bfloat16 b; short s; } u;
    u.b = __float2bfloat16(f);            // RNE; compiler can pair into v_cvt_pk_bf16_f32
    return u.s;
}

// ---------------- kernel 1: w -> exp'd B fragments (256 KB, produced once) ----------------
// EW frag layout: chunk (ut*16 + kb)*64 + cl; cl = (u%16) + 16*g, short8 elem i -> f = 32*kb+8*g+i
__global__ __launch_bounds__(256)
void prep_w(const float* __restrict__ w, unsigned short* __restrict__ ew) {
    const int c   = (blockIdx.x << 8) + threadIdx.x;   // chunk id in [0, 16384)
    const int cl  = c & 63;
    const int ckb = (c >> 6) & 15;
    const int cut = c >> 10;
    const int u   = (cut << 4) + (cl & 15);
    const int gw  = cl >> 4;
    const int fb  = (ckb << 5) + (gw << 3);
    const float s = (u < 128) ? K_L2E : -K_L2E;
    short8 cc;
#pragma unroll
    for (int i = 0; i < 8; ++i)
        cc[i] = f2bf(exp2f(s * w[(fb + i) * U_DIM + u]));
    reinterpret_cast<short8*>(ew)[c] = cc;
}

// ---------------- kernel 2: fused rowstat + exp + MFMA + log -----------------------------
// block = (rt, utq): 16 rows x 64 units, 4 waves, one 16x16 tile per wave.
__global__ __launch_bounds__(256)
void fused_k(const float* __restrict__ x, const unsigned short* __restrict__ ew,
             float* __restrict__ out) {
    __shared__ short8 sA[1024];     // 16 chunks x 64 slots x 16B = 16 KB, XOR-swizzled
    __shared__ float  sst[16];

    const int tid  = threadIdx.x;
    const int wv   = tid >> 6;
    const int lane = tid & 63;
    const int rt   = blockIdx.x >> 2;       // 128 row tiles
    const int utq  = blockIdx.x & 3;
    const int mode = utq >> 1;              // 0: softmax half, 1: softmin half
    const int ut   = (utq << 2) + wv;       // u tile 0..15

    // ---- issue B loads FIRST (L3/L2 latency hides under A-stage) ----
    const short8* Bg = reinterpret_cast<const short8*>(ew) + (ut << 4) * 64 + lane;
    short8 breg[16];
#pragma unroll
    for (int kb = 0; kb < 16; ++kb) breg[kb] = Bg[kb * 64];

    // ---- stage A: load x rows, row-reduce, exp2, write swizzled LDS frags ----
    const int   kb_w = lane >> 2;
    const int   g_w  = lane & 3;
    const float sgn  = mode ? -1.f : 1.f;   // t = sgn*x; max(t) covers both modes

#pragma unroll
    for (int j = 0; j < 4; ++j) {
        const int row = (wv << 2) + j;      // 4 rows per wave -> 16 rows per block
        const float4* xr = reinterpret_cast<const float4*>(x + (rt * 16 + row) * F_DIM);
        float4 v0 = xr[lane * 2];
        float4 v1 = xr[lane * 2 + 1];
        float t[8] = {sgn * v0.x, sgn * v0.y, sgn * v0.z, sgn * v0.w,
                      sgn * v1.x, sgn * v1.y, sgn * v1.z, sgn * v1.w};
        float hi = t[0];
#pragma unroll
        for (int i = 1; i < 8; ++i) hi = fmaxf(hi, t[i]);
#pragma unroll
        for (int off = 32; off; off >>= 1) hi = fmaxf(hi, __shfl_xor(hi, off));
        if (lane == 0) sst[row] = hi;
        short8 cb;
#pragma unroll
        for (int i = 0; i < 8; ++i) cb[i] = f2bf(exp2f(K_L2E * (t[i] - hi)));
        sA[(kb_w << 6) + ((row + (g_w << 4)) ^ (kb_w & 7))] = cb;
    }
    __syncthreads();

    // ---- MFMA loop: A from LDS (conflict-free swizzled), B from VGPRs ----
    f32x4 acc = {0.f, 0.f, 0.f, 0.f};
#pragma unroll
    for (int kb = 0; kb < 16; ++kb) {
        short8 a = sA[(kb << 6) + (lane ^ (kb & 7))];
        acc = __builtin_amdgcn_mfma_f32_16x16x32_bf16(a, breg[kb], acc, 0, 0, 0);
    }

    // ---- epilogue: C/D layout col = lane&15, row = (lane>>4)*4 + r ----
    const int j    = lane & 15;
    const int quad = lane >> 4;
#pragma unroll
    for (int r = 0; r < 4; ++r) {
        const int row = (quad << 2) + r;
        float res = sst[row] + __log2f(acc[r]) * INV_K;
        out[(rt * 16 + row) * U_DIM + (ut << 4) + j] = mode ? -res : res;
    }
}

extern "C" void kernel_launch(void* const* d_in, const int* in_sizes, int n_in,
                              void* d_out, int out_size, void* d_ws, size_t ws_size,
                              hipStream_t stream) {
    const float* x = (const float*)d_in[0];
    const float* w = (const float*)d_in[1];
    float* out = (float*)d_out;
    unsigned short* ew = (unsigned short*)d_ws;   // 16*16*64*8 bf16 = 256 KB

    prep_w<<<64, 256, 0, stream>>>(w, ew);
    fused_k<<<512, 256, 0, stream>>>(x, ew, out);
}